// Round 2
// baseline (445.425 us; speedup 1.0000x reference)
//
#include <hip/hip_runtime.h>
#include <hip/hip_bf16.h>
#include <math.h>

#define Hdim 512
#define Bdim 32
#define Sdim 2048
#define Kdim 1024            // 2*H
#define Mtot (Bdim * Sdim)   // 65536 rows

// scores GEMM v2: block = 1024 thr = 16 waves; tile 128 rows x 512 cols;
// wave w owns cols [32w, 32w+32). BK=64.
// Rationale: BM=64 was vector-memory-path bound (B-frag reloads = 4x A bytes,
// ~50 B/cyc/CU demanded vs ~56 available). BM=128 halves B bytes per row ->
// ~29 B/cyc, HBM-bound again. 2-deep A prefetch + pre-barrier B loads keep
// the stream going with only 1 resident block/CU.
#define BM 128
#define BK 64

typedef __attribute__((ext_vector_type(8))) short short8;
typedef __attribute__((ext_vector_type(4))) float floatx4;

// ---------------- fp32 -> bf16 (RNE) ----------------------------------------
__device__ __forceinline__ short f2bf(float f) {
    union { float f; unsigned u; } v; v.f = f;
    unsigned r = v.u + 0x7fffu + ((v.u >> 16) & 1u);
    return (short)(r >> 16);
}

// 8 fp32 -> 8 bf16 via packed converts
__device__ __forceinline__ short8 cvt8(float4 a, float4 b) {
    union { short8 s; __hip_bfloat162 h[4]; } u;
    u.h[0] = __float22bfloat162_rn(make_float2(a.x, a.y));
    u.h[1] = __float22bfloat162_rn(make_float2(a.z, a.w));
    u.h[2] = __float22bfloat162_rn(make_float2(b.x, b.y));
    u.h[3] = __float22bfloat162_rn(make_float2(b.z, b.w));
    return u.s;
}

__device__ __forceinline__ float fast_tanh(float x) {
    float ax = fabsf(x);
    float e  = __expf(-2.0f * ax);
    float r  = (1.0f - e) * __builtin_amdgcn_rcpf(1.0f + e);
    return copysignf(r, x);
}

// ---------------- Kernel 0: prep --------------------------------------------
// blocks 0..511: W_e fp32 [k][n] -> bf16 PACKED in MFMA-fragment order:
//   short8 index = (nt*32 + ks)*64 + lane,  lane = quad*16 + (n&15),
//   holding B[n = nt*16 + (n&15)][k = ks*32 + quad*8 .. +7].
// blocks 512..639: dec_proj = decoder_hide @ W_h + b_attn.
__global__ __launch_bounds__(256) void prep_kernel(
    const float* __restrict__ W_attn, const float* __restrict__ dec,
    const float* __restrict__ b_attn, short* __restrict__ Wbp,
    float* __restrict__ dec_proj)
{
    const int t = threadIdx.x;
    if (blockIdx.x < 512) {
        const float* We = W_attn + Hdim * Hdim;   // [1024][512]
        __shared__ short tile[32][33];            // [k_loc][n_loc]
        const int k0 = (blockIdx.x >> 4) * 32;
        const int n0 = (blockIdx.x & 15) * 32;
        const int r = t >> 5, c = t & 31;
        #pragma unroll
        for (int rr = 0; rr < 4; ++rr)
            tile[r + rr * 8][c] = f2bf(We[(size_t)(k0 + r + rr * 8) * Hdim + n0 + c]);
        __syncthreads();
        if (t < 128) {
            const int n_loc = t >> 2;             // 0..31
            const int q     = t & 3;              // quad = (k>>3)&3
            const int nt    = (n0 + n_loc) >> 4;
            const int lnn   = (n0 + n_loc) & 15;
            const int ks    = k0 >> 5;
            short8 v;
            #pragma unroll
            for (int r2 = 0; r2 < 8; ++r2) v[r2] = tile[q * 8 + r2][n_loc];
            ((short8*)Wbp)[((nt * 32 + ks) * 64) + q * 16 + lnn] = v;
        }
    } else {
        __shared__ float partl[2][128];
        const int bid = blockIdx.x - 512;      // 0..127
        const int b  = bid >> 2;
        const int cb = bid & 3;
        const int c  = cb * 128 + (t & 127);
        const int kh = t >> 7;
        float acc = 0.0f;
        const int kbeg = kh * 256, kend = kbeg + 256;
        #pragma unroll 8
        for (int k = kbeg; k < kend; ++k)
            acc = fmaf(dec[b * Hdim + k], W_attn[(size_t)k * Hdim + c], acc);
        partl[kh][t & 127] = acc;
        __syncthreads();
        if (t < 128)
            dec_proj[b * Hdim + cb * 128 + t] = partl[0][t] + partl[1][t] + b_attn[cb * 128 + t];
    }
}

// ---------------- Kernel 1: fused MFMA scores (BM=128) ----------------------
// One K-step: [b loads] -> [ds_write A(kt) from 2-deep stage] -> barrier ->
// [issue A(kt+128) LAST] -> phase0 (b0) -> phase1 (b1).
// vmcnt discipline (in-order queue): write waits vmcnt(6) (other stage + b
// stay in flight); b0 at vmcnt(4); b1 at vmcnt(2); the in-flight A stage is
// never drained early.
__device__ __forceinline__ void kstep(
    int kt, short* __restrict__ Ab, float4& ra, float4& rb,
    const float* __restrict__ Ag, const short8* __restrict__ Bp,
    int w, int abase, int pf0, int pf1, int awo,
    floatx4 (&acc)[8][2])
{
    const size_t ks = (size_t)(kt >> 5);
    const size_t nt0 = (size_t)(w * 2 + 0) * 32;
    const size_t nt1 = (size_t)(w * 2 + 1) * 32;
    // B loads first: fly across the barrier (consumed at vmcnt(4)/(2))
    short8 b0[2], b1[2];
    b0[0] = Bp[(nt0 + ks) * 64];
    b0[1] = Bp[(nt1 + ks) * 64];
    b1[0] = Bp[(nt0 + ks + 1) * 64];
    b1[1] = Bp[(nt1 + ks + 1) * 64];

    // stage A(kt) from regs prefetched 2 iterations ago (swizzled write)
    *(short8*)&Ab[awo] = cvt8(ra, rb);
    __syncthreads();

    // A prefetch for kt+2*BK, issued LAST so nothing after it drains vmcnt
    if (kt + 2 * BK < Kdim) {
        const float4* g = (const float4*)(Ag + kt + 2 * BK);
        ra = g[0]; rb = g[1];
    }

    short8 af[4];
    // ---- phase 0: k = kt..kt+31 (logical chunks 0..3 at pf0) ----
    #pragma unroll
    for (int i2 = 0; i2 < 4; ++i2)
        af[i2] = *(const short8*)&Ab[abase + i2 * 1024 + pf0];
    #pragma unroll
    for (int i2 = 0; i2 < 4; ++i2)
        #pragma unroll
        for (int j = 0; j < 2; ++j)
            acc[i2][j] = __builtin_amdgcn_mfma_f32_16x16x32_bf16(
                             af[i2], b0[j], acc[i2][j], 0, 0, 0);
    #pragma unroll
    for (int i2 = 0; i2 < 4; ++i2)
        af[i2] = *(const short8*)&Ab[abase + (i2 + 4) * 1024 + pf0];
    #pragma unroll
    for (int i2 = 0; i2 < 4; ++i2)
        #pragma unroll
        for (int j = 0; j < 2; ++j)
            acc[i2 + 4][j] = __builtin_amdgcn_mfma_f32_16x16x32_bf16(
                                 af[i2], b0[j], acc[i2 + 4][j], 0, 0, 0);
    // ---- phase 1: k = kt+32..kt+63 (logical chunks 4..7 at pf1) ----
    #pragma unroll
    for (int i2 = 0; i2 < 4; ++i2)
        af[i2] = *(const short8*)&Ab[abase + i2 * 1024 + pf1];
    #pragma unroll
    for (int i2 = 0; i2 < 4; ++i2)
        #pragma unroll
        for (int j = 0; j < 2; ++j)
            acc[i2][j] = __builtin_amdgcn_mfma_f32_16x16x32_bf16(
                             af[i2], b1[j], acc[i2][j], 0, 0, 0);
    #pragma unroll
    for (int i2 = 0; i2 < 4; ++i2)
        af[i2] = *(const short8*)&Ab[abase + (i2 + 4) * 1024 + pf1];
    #pragma unroll
    for (int i2 = 0; i2 < 4; ++i2)
        #pragma unroll
        for (int j = 0; j < 2; ++j)
            acc[i2 + 4][j] = __builtin_amdgcn_mfma_f32_16x16x32_bf16(
                                 af[i2], b1[j], acc[i2 + 4][j], 0, 0, 0);
}

__global__ __launch_bounds__(1024, 4) void scores_kernel(
    const float* __restrict__ enc,      // [65536][1024] fp32
    const short* __restrict__ Wbp,      // packed B fragments (1 MB, L2-resident)
    const float* __restrict__ dec_proj, // [32][512]
    const float* __restrict__ v_w,      // [512]
    float* __restrict__ scores)         // [65536]
{
    __shared__ __align__(16) short Asm[2 * BM * BK];   // 32 KB double-buffered
    __shared__ float redl[BM][16];                     // 8 KB

    const int t    = threadIdx.x;
    const int row0 = blockIdx.x * BM;
    const int b    = row0 / Sdim;        // uniform per block (16 blocks/batch)

    const int w    = t >> 6;             // wave 0..15 -> cols [32w, 32w+32)
    const int lane = t & 63;
    const int ln   = lane & 15;
    const int quad = lane >> 4;

    // ---- A staging: thread -> (row sm 0..127, 8-float chunk sq), short8 write
    const int sm = t >> 3;
    const int sq = t & 7;
    const float* Ag = enc + (size_t)(row0 + sm) * Kdim + sq * 8;
    const int awo = sm * BK + ((sq ^ (sm & 7)) * 8);

    // ---- A frag read addresses (verified XOR-swizzle family) ----
    const int abase = ln * BK;                     // + i*1024 (imm) + pf
    const int pf0 = (quad ^ (ln & 7)) * 8;         // logical chunks 0..3
    const int pf1 = pf0 ^ 32;                      // logical chunks 4..7

    // ---- B packed per-lane base ----
    const short8* Bp = ((const short8*)Wbp) + lane;

    floatx4 acc[8][2];
    #pragma unroll
    for (int i = 0; i < 8; ++i)
        #pragma unroll
        for (int j = 0; j < 2; ++j)
            acc[i][j] = (floatx4)(0.0f);

    // ---- prologue: 2-deep prefetch of A tiles kt=0 and kt=64 ----
    float4 r0a, r0b, r1a, r1b;
    { const float4* g = (const float4*)Ag;        r0a = g[0]; r0b = g[1]; }
    { const float4* g = (const float4*)(Ag + BK); r1a = g[0]; r1b = g[1]; }

    for (int kt = 0; kt < Kdim; kt += 2 * BK) {
        kstep(kt,      Asm,           r0a, r0b, Ag, Bp, w, abase, pf0, pf1, awo, acc);
        kstep(kt + BK, Asm + BM * BK, r1a, r1b, Ag, Bp, w, abase, pf0, pf1, awo, acc);
    }

    // ---- epilogue: +dec_proj, tanh, *v_w; wave sums its 32 cols ----
    float dpv[2], vwv[2];
    #pragma unroll
    for (int j = 0; j < 2; ++j) {
        const int col = w * 32 + j * 16 + ln;
        dpv[j] = dec_proj[b * Hdim + col];
        vwv[j] = v_w[col];
    }
    #pragma unroll
    for (int i = 0; i < 8; ++i) {
        #pragma unroll
        for (int reg = 0; reg < 4; ++reg) {
            float s = 0.0f;
            #pragma unroll
            for (int j = 0; j < 2; ++j) {
                float x = acc[i][j][reg] + dpv[j];
                s = fmaf(vwv[j], fast_tanh(x), s);
            }
            s += __shfl_xor(s, 1, 64);
            s += __shfl_xor(s, 2, 64);
            s += __shfl_xor(s, 4, 64);
            s += __shfl_xor(s, 8, 64);
            if (ln == 0)
                redl[i * 16 + quad * 4 + reg][w] = s;
        }
    }
    __syncthreads();
    if (t < BM) {
        float s = 0.0f;
        #pragma unroll
        for (int wv = 0; wv < 16; ++wv) s += redl[t][wv];
        scores[row0 + t] = s;
    }
}

// ---------------- Kernel 2: masked softmax over S per batch -----------------
__global__ __launch_bounds__(256) void softmax_kernel(
    const float* __restrict__ scores, const int* __restrict__ mask,
    float* __restrict__ out)
{
    __shared__ float sred[8];
    const int b = blockIdx.x;
    const int t = threadIdx.x;
    const int lane = t & 63;
    const int wid  = t >> 6;

    float x[8];
    float m = -1e30f;
    #pragma unroll
    for (int j = 0; j < 8; ++j) {
        int idx = b * Sdim + j * 256 + t;
        float v = scores[idx];
        if (mask[idx] == 0) v = -100000.0f;
        x[j] = v;
        m = fmaxf(m, v);
    }
    #pragma unroll
    for (int off = 32; off >= 1; off >>= 1)
        m = fmaxf(m, __shfl_xor(m, off, 64));
    if (lane == 0) sred[wid] = m;
    __syncthreads();
    m = fmaxf(fmaxf(sred[0], sred[1]), fmaxf(sred[2], sred[3]));

    float s = 0.0f;
    #pragma unroll
    for (int j = 0; j < 8; ++j) {
        float e = __expf(x[j] - m);
        x[j] = e;
        s += e;
    }
    #pragma unroll
    for (int off = 32; off >= 1; off >>= 1)
        s += __shfl_xor(s, off, 64);
    if (lane == 0) sred[4 + wid] = s;
    __syncthreads();
    s = sred[4] + sred[5] + sred[6] + sred[7];

    const float inv = 1.0f / s;
    #pragma unroll
    for (int j = 0; j < 8; ++j)
        out[b * Sdim + j * 256 + t] = x[j] * inv;
}

// ---------------- launch ----------------------------------------------------
extern "C" void kernel_launch(void* const* d_in, const int* in_sizes, int n_in,
                              void* d_out, int out_size, void* d_ws, size_t ws_size,
                              hipStream_t stream) {
    const float* dec  = (const float*)d_in[0];   // (B, H)
    const float* enc  = (const float*)d_in[1];   // (B, S, 2H)
    const int*   mask = (const int*)  d_in[2];   // (B, S)
    const float* W    = (const float*)d_in[3];   // (3H, H)
    const float* ba   = (const float*)d_in[4];   // (H,)
    const float* vw   = (const float*)d_in[5];   // (H,)
    float* out = (float*)d_out;                  // (B, S)

    // workspace layout (~1.3 MB)
    float* dec_proj = (float*)d_ws;                       // 32*512 f   = 64 KB
    short* Wbp      = (short*)(dec_proj + Bdim * Hdim);   // 512*1024 s = 1 MB (packed)
    float* scores   = (float*)(Wbp + Hdim * Kdim);        // 65536 f    = 256 KB

    prep_kernel<<<640, 256, 0, stream>>>(W, dec, ba, Wbp, dec_proj);
    scores_kernel<<<Mtot / BM, 1024, 0, stream>>>(enc, Wbp, dec_proj, vw, scores);
    softmax_kernel<<<Bdim, 256, 0, stream>>>(scores, mask, out);
}

// Round 3
// 427.526 us; speedup vs baseline: 1.0419x; 1.0419x over previous
//
#include <hip/hip_runtime.h>
#include <hip/hip_bf16.h>
#include <math.h>

#define Hdim 512
#define Bdim 32
#define Sdim 2048
#define Kdim 1024            // 2*H
#define Mtot (Bdim * Sdim)   // 65536 rows

// scores GEMM v3: block = 512 thr = 8 waves; tile 128 rows x 512 cols;
// wave w owns cols [64w, 64w+64) (R7's proven 4-n-tile layout), 128 rows.
// BM=128 halves per-row B traffic vs BM=64 (1 MB B per block covers 2x rows).
// 8-wave blocks keep the 256-reg/thread budget (v2's 16-wave/128-reg build
// spilled ~78 MB of scratch per dispatch). acc[8][4]=128 regs + stage 16 +
// b 32 + af 16 + addr ~25 = ~217 < 256.
#define BM 128
#define BK 64

typedef __attribute__((ext_vector_type(8))) short short8;
typedef __attribute__((ext_vector_type(4))) float floatx4;

// ---------------- fp32 -> bf16 (RNE) ----------------------------------------
__device__ __forceinline__ short f2bf(float f) {
    union { float f; unsigned u; } v; v.f = f;
    unsigned r = v.u + 0x7fffu + ((v.u >> 16) & 1u);
    return (short)(r >> 16);
}

// 8 fp32 -> 8 bf16 via packed converts
__device__ __forceinline__ short8 cvt8(float4 a, float4 b) {
    union { short8 s; __hip_bfloat162 h[4]; } u;
    u.h[0] = __float22bfloat162_rn(make_float2(a.x, a.y));
    u.h[1] = __float22bfloat162_rn(make_float2(a.z, a.w));
    u.h[2] = __float22bfloat162_rn(make_float2(b.x, b.y));
    u.h[3] = __float22bfloat162_rn(make_float2(b.z, b.w));
    return u.s;
}

__device__ __forceinline__ float fast_tanh(float x) {
    float ax = fabsf(x);
    float e  = __expf(-2.0f * ax);
    float r  = (1.0f - e) * __builtin_amdgcn_rcpf(1.0f + e);
    return copysignf(r, x);
}

// ---------------- Kernel 0: prep --------------------------------------------
// blocks 0..511: W_e fp32 [k][n] -> bf16 PACKED in MFMA-fragment order:
//   short8 index = (nt*32 + ks)*64 + lane,  lane = quad*16 + (n&15),
//   holding B[n = nt*16 + (n&15)][k = ks*32 + quad*8 .. +7].
// blocks 512..639: dec_proj = decoder_hide @ W_h + b_attn.
__global__ __launch_bounds__(256) void prep_kernel(
    const float* __restrict__ W_attn, const float* __restrict__ dec,
    const float* __restrict__ b_attn, short* __restrict__ Wbp,
    float* __restrict__ dec_proj)
{
    const int t = threadIdx.x;
    if (blockIdx.x < 512) {
        const float* We = W_attn + Hdim * Hdim;   // [1024][512]
        __shared__ short tile[32][33];            // [k_loc][n_loc]
        const int k0 = (blockIdx.x >> 4) * 32;
        const int n0 = (blockIdx.x & 15) * 32;
        const int r = t >> 5, c = t & 31;
        #pragma unroll
        for (int rr = 0; rr < 4; ++rr)
            tile[r + rr * 8][c] = f2bf(We[(size_t)(k0 + r + rr * 8) * Hdim + n0 + c]);
        __syncthreads();
        if (t < 128) {
            const int n_loc = t >> 2;             // 0..31
            const int q     = t & 3;              // quad = (k>>3)&3
            const int nt    = (n0 + n_loc) >> 4;
            const int lnn   = (n0 + n_loc) & 15;
            const int ks    = k0 >> 5;
            short8 v;
            #pragma unroll
            for (int r2 = 0; r2 < 8; ++r2) v[r2] = tile[q * 8 + r2][n_loc];
            ((short8*)Wbp)[((nt * 32 + ks) * 64) + q * 16 + lnn] = v;
        }
    } else {
        __shared__ float partl[2][128];
        const int bid = blockIdx.x - 512;      // 0..127
        const int b  = bid >> 2;
        const int cb = bid & 3;
        const int c  = cb * 128 + (t & 127);
        const int kh = t >> 7;
        float acc = 0.0f;
        const int kbeg = kh * 256, kend = kbeg + 256;
        #pragma unroll 8
        for (int k = kbeg; k < kend; ++k)
            acc = fmaf(dec[b * Hdim + k], W_attn[(size_t)k * Hdim + c], acc);
        partl[kh][t & 127] = acc;
        __syncthreads();
        if (t < 128)
            dec_proj[b * Hdim + cb * 128 + t] = partl[0][t] + partl[1][t] + b_attn[cb * 128 + t];
    }
}

// ---------------- Kernel 1: fused MFMA scores (BM=128, 8 waves) -------------
// One K-step: [b0/b1 loads] -> [ds_write A(kt) from 1-deep stage, waits
// vmcnt(8) so the 8 b-loads stay in flight] -> barrier -> [issue A(kt+BK)
// LAST] -> phase0 (b0, 32 MFMA) -> phase1 (b1, 32 MFMA). In-order vmcnt:
// phase0 drains b0 at vmcnt(8), phase1 b1 at vmcnt(4); the A prefetch is
// never drained early and is covered by a full compute phase.
__device__ __forceinline__ void kstep(
    int kt, short* __restrict__ Ab, float4 (&ra)[4],
    const float* __restrict__ Ag, const short8* __restrict__ Bp,
    int w, int abase, int pf0, int pf1, int awo0, int awo1,
    floatx4 (&acc)[8][4])
{
    const size_t ks = (size_t)(kt >> 5);
    // B loads first: fly across the barrier
    short8 b0[4], b1[4];
    #pragma unroll
    for (int j = 0; j < 4; ++j)
        b0[j] = Bp[((size_t)(w * 4 + j) * 32 + ks) * 64];
    #pragma unroll
    for (int j = 0; j < 4; ++j)
        b1[j] = Bp[((size_t)(w * 4 + j) * 32 + ks + 1) * 64];

    // stage A(kt) from regs prefetched last iteration (swizzled writes)
    *(short8*)&Ab[awo0] = cvt8(ra[0], ra[1]);
    *(short8*)&Ab[awo1] = cvt8(ra[2], ra[3]);
    __syncthreads();

    // A prefetch for kt+BK, issued LAST so nothing after it drains vmcnt
    if (kt + BK < Kdim) {
        const float4* g = (const float4*)(Ag + kt + BK);
        ra[0] = g[0]; ra[1] = g[1]; ra[2] = g[2]; ra[3] = g[3];
    }

    short8 af[4];
    // ---- phase 0: k = kt..kt+31 ----
    #pragma unroll
    for (int i2 = 0; i2 < 4; ++i2)
        af[i2] = *(const short8*)&Ab[abase + i2 * 1024 + pf0];
    #pragma unroll
    for (int i2 = 0; i2 < 4; ++i2)
        #pragma unroll
        for (int j = 0; j < 4; ++j)
            acc[i2][j] = __builtin_amdgcn_mfma_f32_16x16x32_bf16(
                             af[i2], b0[j], acc[i2][j], 0, 0, 0);
    #pragma unroll
    for (int i2 = 0; i2 < 4; ++i2)
        af[i2] = *(const short8*)&Ab[abase + (i2 + 4) * 1024 + pf0];
    #pragma unroll
    for (int i2 = 0; i2 < 4; ++i2)
        #pragma unroll
        for (int j = 0; j < 4; ++j)
            acc[i2 + 4][j] = __builtin_amdgcn_mfma_f32_16x16x32_bf16(
                                 af[i2], b0[j], acc[i2 + 4][j], 0, 0, 0);
    // ---- phase 1: k = kt+32..kt+63 ----
    #pragma unroll
    for (int i2 = 0; i2 < 4; ++i2)
        af[i2] = *(const short8*)&Ab[abase + i2 * 1024 + pf1];
    #pragma unroll
    for (int i2 = 0; i2 < 4; ++i2)
        #pragma unroll
        for (int j = 0; j < 4; ++j)
            acc[i2][j] = __builtin_amdgcn_mfma_f32_16x16x32_bf16(
                             af[i2], b1[j], acc[i2][j], 0, 0, 0);
    #pragma unroll
    for (int i2 = 0; i2 < 4; ++i2)
        af[i2] = *(const short8*)&Ab[abase + (i2 + 4) * 1024 + pf1];
    #pragma unroll
    for (int i2 = 0; i2 < 4; ++i2)
        #pragma unroll
        for (int j = 0; j < 4; ++j)
            acc[i2 + 4][j] = __builtin_amdgcn_mfma_f32_16x16x32_bf16(
                                 af[i2], b1[j], acc[i2 + 4][j], 0, 0, 0);
}

__global__ __launch_bounds__(512, 2) void scores_kernel(
    const float* __restrict__ enc,      // [65536][1024] fp32
    const short* __restrict__ Wbp,      // packed B fragments (1 MB, L2-resident)
    const float* __restrict__ dec_proj, // [32][512]
    const float* __restrict__ v_w,      // [512]
    float* __restrict__ scores)         // [65536]
{
    __shared__ __align__(16) short Asm[2 * BM * BK];   // 32 KB double-buffered
    __shared__ float redl[BM][9];                      // 4.5 KB (padded)

    const int t    = threadIdx.x;
    const int row0 = blockIdx.x * BM;
    const int b    = row0 / Sdim;        // uniform per block (16 blocks/batch)

    const int w    = t >> 6;             // wave 0..7 -> cols [64w, 64w+64)
    const int lane = t & 63;
    const int ln   = lane & 15;
    const int quad = lane >> 4;

    // ---- A staging: thread -> (row sm 0..127, chunks sqb, sqb+1): 64 B ----
    const int sm  = t >> 2;
    const int sqb = (t & 3) * 2;
    const float* Ag = enc + (size_t)(row0 + sm) * Kdim + sqb * 8;
    const int awo0 = sm * BK + ((sqb       ^ (sm & 7)) * 8);
    const int awo1 = sm * BK + (((sqb + 1) ^ (sm & 7)) * 8);

    // ---- A frag read addresses (verified XOR-swizzle family) ----
    const int abase = ln * BK;                     // + i2*1024 (imm) + pf
    const int pf0 = (quad ^ (ln & 7)) * 8;         // phase 0 chunk
    const int pf1 = pf0 ^ 32;                      // phase 1 chunk (^4 in idx)

    // ---- B packed per-lane base ----
    const short8* Bp = ((const short8*)Wbp) + lane;

    floatx4 acc[8][4];
    #pragma unroll
    for (int i = 0; i < 8; ++i)
        #pragma unroll
        for (int j = 0; j < 4; ++j)
            acc[i][j] = (floatx4)(0.0f);

    // ---- prologue: 1-deep prefetch of A tile kt=0 ----
    float4 ra[4];
    { const float4* g = (const float4*)Ag; ra[0] = g[0]; ra[1] = g[1]; ra[2] = g[2]; ra[3] = g[3]; }

    #pragma unroll 1
    for (int kt = 0; kt < Kdim; kt += 2 * BK) {
        kstep(kt,      Asm,           ra, Ag, Bp, w, abase, pf0, pf1, awo0, awo1, acc);
        kstep(kt + BK, Asm + BM * BK, ra, Ag, Bp, w, abase, pf0, pf1, awo0, awo1, acc);
    }

    // ---- epilogue: +dec_proj, tanh, *v_w; wave sums its 64 cols ----
    float dpv[4], vwv[4];
    #pragma unroll
    for (int j = 0; j < 4; ++j) {
        const int col = w * 64 + j * 16 + ln;
        dpv[j] = dec_proj[b * Hdim + col];
        vwv[j] = v_w[col];
    }
    #pragma unroll
    for (int i = 0; i < 8; ++i) {
        #pragma unroll
        for (int reg = 0; reg < 4; ++reg) {
            float s = 0.0f;
            #pragma unroll
            for (int j = 0; j < 4; ++j) {
                float x = acc[i][j][reg] + dpv[j];
                s = fmaf(vwv[j], fast_tanh(x), s);
            }
            s += __shfl_xor(s, 1, 64);
            s += __shfl_xor(s, 2, 64);
            s += __shfl_xor(s, 4, 64);
            s += __shfl_xor(s, 8, 64);
            if (ln == 0)
                redl[i * 16 + quad * 4 + reg][w] = s;
        }
    }
    __syncthreads();
    if (t < BM) {
        float s = 0.0f;
        #pragma unroll
        for (int wv = 0; wv < 8; ++wv) s += redl[t][wv];
        scores[row0 + t] = s;
    }
}

// ---------------- Kernel 2: masked softmax over S per batch -----------------
__global__ __launch_bounds__(256) void softmax_kernel(
    const float* __restrict__ scores, const int* __restrict__ mask,
    float* __restrict__ out)
{
    __shared__ float sred[8];
    const int b = blockIdx.x;
    const int t = threadIdx.x;
    const int lane = t & 63;
    const int wid  = t >> 6;

    float x[8];
    float m = -1e30f;
    #pragma unroll
    for (int j = 0; j < 8; ++j) {
        int idx = b * Sdim + j * 256 + t;
        float v = scores[idx];
        if (mask[idx] == 0) v = -100000.0f;
        x[j] = v;
        m = fmaxf(m, v);
    }
    #pragma unroll
    for (int off = 32; off >= 1; off >>= 1)
        m = fmaxf(m, __shfl_xor(m, off, 64));
    if (lane == 0) sred[wid] = m;
    __syncthreads();
    m = fmaxf(fmaxf(sred[0], sred[1]), fmaxf(sred[2], sred[3]));

    float s = 0.0f;
    #pragma unroll
    for (int j = 0; j < 8; ++j) {
        float e = __expf(x[j] - m);
        x[j] = e;
        s += e;
    }
    #pragma unroll
    for (int off = 32; off >= 1; off >>= 1)
        s += __shfl_xor(s, off, 64);
    if (lane == 0) sred[4 + wid] = s;
    __syncthreads();
    s = sred[4] + sred[5] + sred[6] + sred[7];

    const float inv = 1.0f / s;
    #pragma unroll
    for (int j = 0; j < 8; ++j)
        out[b * Sdim + j * 256 + t] = x[j] * inv;
}

// ---------------- launch ----------------------------------------------------
extern "C" void kernel_launch(void* const* d_in, const int* in_sizes, int n_in,
                              void* d_out, int out_size, void* d_ws, size_t ws_size,
                              hipStream_t stream) {
    const float* dec  = (const float*)d_in[0];   // (B, H)
    const float* enc  = (const float*)d_in[1];   // (B, S, 2H)
    const int*   mask = (const int*)  d_in[2];   // (B, S)
    const float* W    = (const float*)d_in[3];   // (3H, H)
    const float* ba   = (const float*)d_in[4];   // (H,)
    const float* vw   = (const float*)d_in[5];   // (H,)
    float* out = (float*)d_out;                  // (B, S)

    // workspace layout (~1.3 MB)
    float* dec_proj = (float*)d_ws;                       // 32*512 f   = 64 KB
    short* Wbp      = (short*)(dec_proj + Bdim * Hdim);   // 512*1024 s = 1 MB (packed)
    float* scores   = (float*)(Wbp + Hdim * Kdim);        // 65536 f    = 256 KB

    prep_kernel<<<640, 256, 0, stream>>>(W, dec, ba, Wbp, dec_proj);
    scores_kernel<<<Mtot / BM, 512, 0, stream>>>(enc, Wbp, dec_proj, vw, scores);
    softmax_kernel<<<Bdim, 256, 0, stream>>>(scores, mask, out);
}